// Round 1
// 1676.884 us; speedup vs baseline: 1.2968x; 1.2968x over previous
//
#include <hip/hip_runtime.h>
#include <hip/hip_bf16.h>
#include <cstdint>
#include <cstddef>

typedef __bf16 bf16_t;
typedef __attribute__((ext_vector_type(8))) __bf16 bf16x8;
typedef __attribute__((ext_vector_type(4))) float floatx4;

#define CFENCE asm volatile("" ::: "memory")

// ---------------------------------------------------------------------------
// async global->LDS, 16B per lane. LDS dest is wave-uniform base + lane*16.
// ---------------------------------------------------------------------------
__device__ __forceinline__ void load_lds_16B(const void* g, void* l) {
  __builtin_amdgcn_global_load_lds(
      (__attribute__((address_space(1))) void*)(uintptr_t)g,
      (__attribute__((address_space(3))) void*)l,
      16, 0, 0);
}

// ---------------------------------------------------------------------------
// Pre-pass 1: x fp32 -> bf16  (8 elements / thread)
// ---------------------------------------------------------------------------
__global__ __launch_bounds__(256) void cast_x_kernel(
    const float* __restrict__ in, bf16_t* __restrict__ out, size_t n) {
  size_t i = ((size_t)blockIdx.x * 256 + threadIdx.x) * 8;
  if (i + 8 > n) return;
  const float4* p = (const float4*)(in + i);
  float4 a = p[0], b = p[1];
  bf16x8 v;
  v[0] = (bf16_t)a.x; v[1] = (bf16_t)a.y; v[2] = (bf16_t)a.z; v[3] = (bf16_t)a.w;
  v[4] = (bf16_t)b.x; v[5] = (bf16_t)b.y; v[6] = (bf16_t)b.z; v[7] = (bf16_t)b.w;
  *(bf16x8*)(out + i) = v;
}

// ---------------------------------------------------------------------------
// Pre-pass 2: W fp32 [N,K] * blockscale[(n/128),(k/128)] -> bf16
// ---------------------------------------------------------------------------
__global__ __launch_bounds__(256) void dequant_w_kernel(
    const float* __restrict__ w, const float* __restrict__ s,
    bf16_t* __restrict__ out, int K, int KB) {
  const int row = blockIdx.x;
  const int k = (blockIdx.y * 256 + threadIdx.x) * 8;
  const float sc = s[(row >> 7) * KB + (k >> 7)];
  const size_t i = (size_t)row * K + k;
  const float4* p = (const float4*)(w + i);
  float4 a = p[0], b = p[1];
  bf16x8 v;
  v[0] = (bf16_t)(a.x * sc); v[1] = (bf16_t)(a.y * sc);
  v[2] = (bf16_t)(a.z * sc); v[3] = (bf16_t)(a.w * sc);
  v[4] = (bf16_t)(b.x * sc); v[5] = (bf16_t)(b.y * sc);
  v[6] = (bf16_t)(b.z * sc); v[7] = (bf16_t)(b.w * sc);
  *(bf16x8*)(out + i) = v;
}

// ---------------------------------------------------------------------------
// GEMM: C[M,N] = A[M,K] * B[N,K]^T + bias
// 256x256 tile, BK=64, 512 threads (8 waves, 2M x 4N), 8-phase schedule with
// counted vmcnt(6) (T3+T4), LDS XOR-swizzle (T2), setprio (T5), XCD swizzle
// (T1).  LDS: 2 buffers x (A 32KB + B 32KB) = 128 KiB, 1 WG/CU.
//
// Swizzle: logical byte L at row r maps to physical L ^ ((r&7)<<4).
// global_load_lds writes LDS linearly, so the *source* address is
// pre-swizzled with the same involution (rule #21: both-sides-or-neither).
//
// Stage units: A_e = rows [0,64)u[128,192)  (read at the phase computing the
// i-half0 quadrants), A_l = rows [64,128)u[192,256); same split for B.
// Ledger (iter t computes tiles 2t (buf0, P1-4) and 2t+1 (buf1, P5-8)):
//   P1 stage (2t+1).A_l->buf1   P5 stage (2t+2).A_l->buf0
//   P2 stage (2t+2).A_e->buf0   P6 stage (2t+3).A_e->buf1
//   P3 stage (2t+2).B_e->buf0   P7 stage (2t+3).B_e->buf1
//   P4 stage (2t+2).B_l->buf0   P8 stage (2t+3).B_l->buf1
// Every stage is >=1 barrier after the region's last ds_read; vmcnt(6) at
// P4/P8 leaves exactly the newest 3 half-tiles in flight, so each tile is
// fully arrived (+barrier-published) before its first read.  Last iteration
// prefetches wrap k mod K (in-bounds, never consumed) to keep counts uniform.
// ---------------------------------------------------------------------------
__global__ __launch_bounds__(512, 2) void gemm256_kernel(
    const bf16_t* __restrict__ A, const bf16_t* __restrict__ B,
    const float* __restrict__ bias, float* __restrict__ C,
    int M, int N, int K) {
  __shared__ __align__(16) unsigned char lds[2][2][32768];  // [buf][A/B][bytes]

  const int tid  = threadIdx.x;
  const int wave = tid >> 6;
  const int lane = tid & 63;
  const int lm   = lane & 15;
  const int quad = lane >> 4;
  const int wm   = wave >> 2;  // 0..1
  const int wn   = wave & 3;   // 0..3

  // T1: bijective XCD-aware block swizzle (m204)
  const int nbn = N >> 8;
  const int nwg = gridDim.x;
  const int q8 = nwg >> 3, r8 = nwg & 7;
  const int xcd = blockIdx.x & 7, lid = blockIdx.x >> 3;
  const int sid = (xcd < r8 ? xcd * (q8 + 1) : r8 * (q8 + 1) + (xcd - r8) * q8) + lid;
  const int bm = sid / nbn;
  const int bn = sid % nbn;

  const size_t K2 = (size_t)K * 2;  // row stride in bytes
  const char* Ag = (const char*)A + (size_t)bm * 256 * K2;
  const char* Bg = (const char*)B + (size_t)bn * 256 * K2;

  const int lrow8 = lane >> 3;                       // row-in-group for staging
  const int lcb   = ((lane & 7) ^ lrow8) << 4;       // pre-swizzled source col-byte
  const int swz   = (lane & 7) << 4;                 // read-side swizzle key (row&7 == lane&7)
  const int rowA  = wm * 128 + lm;
  const int rowB  = wn * 64 + lm;

  const int NT = K >> 6;  // K-tiles of 64 (K % 128 == 0 assumed)

  floatx4 acc[8][4] = {};
  bf16x8  af[4][2];       // current A i-half fragments [i][kk]
  bf16x8  bb[2][2][2];    // B fragments [jh][j][kk], both halves resident

#define STAGE(gbase, op_, u_, kt_, buf_)                                         \
  do {                                                                           \
    _Pragma("unroll") for (int c_ = 0; c_ < 2; ++c_) {                           \
      const int r_ = (u_) * 64 + c_ * 128 + wave * 8 + lrow8;                    \
      load_lds_16B((gbase) + (size_t)r_ * K2 + (size_t)(kt_) * 128 + lcb,        \
                   &lds[buf_][op_][((u_) * 64 + c_ * 128) * 128 + wave * 1024]); \
    }                                                                            \
  } while (0)

#define LD_A(buf_, ih_)                                                          \
  do {                                                                           \
    const unsigned char* R_ = &lds[buf_][0][0];                                  \
    _Pragma("unroll") for (int i_ = 0; i_ < 4; ++i_) {                           \
      const int r_ = rowA + (ih_) * 64 + i_ * 16;                                \
      _Pragma("unroll") for (int kk_ = 0; kk_ < 2; ++kk_)                        \
        af[i_][kk_] = *(const bf16x8*)(R_ + r_ * 128 +                           \
                                       ((kk_ * 64 + quad * 16) ^ swz));          \
    }                                                                            \
  } while (0)

#define LD_B(buf_, jh_)                                                          \
  do {                                                                           \
    const unsigned char* R_ = &lds[buf_][1][0];                                  \
    _Pragma("unroll") for (int j_ = 0; j_ < 2; ++j_) {                           \
      const int r_ = rowB + (jh_) * 32 + j_ * 16;                                \
      _Pragma("unroll") for (int kk_ = 0; kk_ < 2; ++kk_)                        \
        bb[jh_][j_][kk_] = *(const bf16x8*)(R_ + r_ * 128 +                      \
                                            ((kk_ * 64 + quad * 16) ^ swz));     \
    }                                                                            \
  } while (0)

#define MFMA16(ih_, jh_)                                                         \
  do {                                                                           \
    _Pragma("unroll") for (int i_ = 0; i_ < 4; ++i_)                             \
      _Pragma("unroll") for (int j_ = 0; j_ < 2; ++j_) {                         \
        acc[(ih_) * 4 + i_][(jh_) * 2 + j_] =                                    \
            __builtin_amdgcn_mfma_f32_16x16x32_bf16(                             \
                af[i_][0], bb[jh_][j_][0],                                       \
                acc[(ih_) * 4 + i_][(jh_) * 2 + j_], 0, 0, 0);                   \
        acc[(ih_) * 4 + i_][(jh_) * 2 + j_] =                                    \
            __builtin_amdgcn_mfma_f32_16x16x32_bf16(                             \
                af[i_][1], bb[jh_][j_][1],                                       \
                acc[(ih_) * 4 + i_][(jh_) * 2 + j_], 0, 0, 0);                   \
      }                                                                          \
  } while (0)

#define PH_OPEN()                                                                \
  do {                                                                           \
    CFENCE;                                                                      \
    __builtin_amdgcn_s_barrier();                                                \
    asm volatile("s_waitcnt lgkmcnt(0)" ::: "memory");                           \
    __builtin_amdgcn_sched_barrier(0);                                           \
    __builtin_amdgcn_s_setprio(1);                                               \
  } while (0)

#define PH_CLOSE()                                                               \
  do {                                                                           \
    __builtin_amdgcn_s_setprio(0);                                               \
    CFENCE;                                                                      \
    __builtin_amdgcn_s_barrier();                                                \
    CFENCE;                                                                      \
  } while (0)

#define PH_CLOSE_VM()                                                            \
  do {                                                                           \
    __builtin_amdgcn_s_setprio(0);                                               \
    asm volatile("s_waitcnt vmcnt(6)" ::: "memory");                             \
    CFENCE;                                                                      \
    __builtin_amdgcn_s_barrier();                                                \
    CFENCE;                                                                      \
  } while (0)

  // ---- prologue: tile0 complete + tile1 {A_e, B_e, B_l}; tile1.A_l at P1 ----
  STAGE(Ag, 0, 0, 0, 0);
  STAGE(Ag, 0, 1, 0, 0);
  STAGE(Bg, 1, 0, 0, 0);
  STAGE(Bg, 1, 1, 0, 0);
  STAGE(Ag, 0, 0, 1, 1);
  STAGE(Bg, 1, 0, 1, 1);
  STAGE(Bg, 1, 1, 1, 1);
  asm volatile("s_waitcnt vmcnt(6)" ::: "memory");  // tile0 arrived, 3 units in flight
  CFENCE;
  __builtin_amdgcn_s_barrier();
  CFENCE;

#pragma unroll 1
  for (int t = 0; t < NT / 2; ++t) {
    const int k1 = 2 * t + 1;
    int k2 = 2 * t + 2; if (k2 >= NT) k2 -= NT;   // wrapped prefetch, never consumed
    int k3 = 2 * t + 3; if (k3 >= NT) k3 -= NT;

    // ---- P1: buf0 quadrant (i-half0 x j-half0) ----
    LD_A(0, 0); LD_B(0, 0);
    STAGE(Ag, 0, 1, k1, 1);
    PH_OPEN(); MFMA16(0, 0); PH_CLOSE();
    // ---- P2: (i-half0 x j-half1) ----
    LD_B(0, 1);
    STAGE(Ag, 0, 0, k2, 0);
    PH_OPEN(); MFMA16(0, 1); PH_CLOSE();
    // ---- P3: (i-half1 x j-half0) ----
    LD_A(0, 1);
    STAGE(Bg, 1, 0, k2, 0);
    PH_OPEN(); MFMA16(1, 0); PH_CLOSE();
    // ---- P4: (i-half1 x j-half1); counted vmcnt ----
    STAGE(Bg, 1, 1, k2, 0);
    PH_OPEN(); MFMA16(1, 1); PH_CLOSE_VM();
    // ---- P5: buf1 quadrant (i-half0 x j-half0) ----
    LD_A(1, 0); LD_B(1, 0);
    STAGE(Ag, 0, 1, k2, 0);
    PH_OPEN(); MFMA16(0, 0); PH_CLOSE();
    // ---- P6 ----
    LD_B(1, 1);
    STAGE(Ag, 0, 0, k3, 1);
    PH_OPEN(); MFMA16(0, 1); PH_CLOSE();
    // ---- P7 ----
    LD_A(1, 1);
    STAGE(Bg, 1, 0, k3, 1);
    PH_OPEN(); MFMA16(1, 0); PH_CLOSE();
    // ---- P8 ----
    STAGE(Bg, 1, 1, k3, 1);
    PH_OPEN(); MFMA16(1, 1); PH_CLOSE_VM();
  }

  // ---- epilogue: C/D layout col=lane&15, row=quad*4+r  [m89/m91] ----
  const int cm0 = bm * 256 + wm * 128 + quad * 4;
  const int cn0 = bn * 256 + wn * 64 + lm;
#pragma unroll
  for (int j = 0; j < 4; ++j) {
    const int n = cn0 + j * 16;
    const float bv = bias[n];
#pragma unroll
    for (int i = 0; i < 8; ++i) {
      const int m0 = cm0 + i * 16;
#pragma unroll
      for (int r = 0; r < 4; ++r)
        C[(size_t)(m0 + r) * N + n] = acc[i][j][r] + bv;
    }
  }

#undef STAGE
#undef LD_A
#undef LD_B
#undef MFMA16
#undef PH_OPEN
#undef PH_CLOSE
#undef PH_CLOSE_VM
}

// ---------------------------------------------------------------------------
extern "C" void kernel_launch(void* const* d_in, const int* in_sizes, int n_in,
                              void* d_out, int out_size, void* d_ws, size_t ws_size,
                              hipStream_t stream) {
  const float* x    = (const float*)d_in[0];  // [M,K]
  const float* w    = (const float*)d_in[1];  // [N,K]
  const float* s    = (const float*)d_in[2];  // [N/128, K/128]
  const float* bias = (const float*)d_in[3];  // [N]
  float* out = (float*)d_out;                 // [M,N]

  const int N  = in_sizes[3];
  const int K  = (int)((long long)in_sizes[1] / N);
  const int M  = (int)((long long)in_sizes[0] / K);
  const int KB = K / 128;

  bf16_t* xb = (bf16_t*)d_ws;                 // M*K bf16
  bf16_t* wb = xb + (size_t)M * K;            // N*K bf16

  const size_t nx = (size_t)M * K;
  cast_x_kernel<<<(int)(nx / 2048), 256, 0, stream>>>(x, xb, nx);

  dim3 gw(N, K / 2048);
  dequant_w_kernel<<<gw, 256, 0, stream>>>(w, s, wb, K, KB);

  const int nwg = (M / 256) * (N / 256);
  gemm256_kernel<<<nwg, 512, 0, stream>>>(xb, wb, bias, out, M, N, K);
}